// Round 1
// baseline (272.222 us; speedup 1.0000x reference)
//
#include <hip/hip_runtime.h>

#define N_NODES 100000
#define N_EDGES 400000
#define HID 32

// ---------------- conv1 edge kernel ----------------
// thread = (edge e, out-channel o). msg[e][o] = sum_d x[src][d] * We1[e][d][o],
// We1[e][d][o] = sum_d2 ea[e][d2]*Wn1[d2][d*32+o] + bn1[d*32+o]
__global__ __launch_bounds__(256) void edge1_kernel(
    const int* __restrict__ ei, const float* __restrict__ x,
    const float* __restrict__ ea, const float* __restrict__ Wn1,
    const float* __restrict__ bn1, float* __restrict__ agg)
{
    int gid = blockIdx.x * 256 + threadIdx.x;
    int e = gid >> 5, o = gid & 31;
    if (e >= N_EDGES) return;
    int s = ei[e], d = ei[N_EDGES + e];
    float ea0 = ea[e*3+0], ea1 = ea[e*3+1], ea2 = ea[e*3+2];
    float xs0 = x[s*3+0], xs1 = x[s*3+1], xs2 = x[s*3+2];
    float m = 0.f;
    {
        int k = o;
        float w = fmaf(ea0, Wn1[k], fmaf(ea1, Wn1[96+k], fmaf(ea2, Wn1[192+k], bn1[k])));
        m = fmaf(xs0, w, m);
        k = 32 + o;
        w = fmaf(ea0, Wn1[k], fmaf(ea1, Wn1[96+k], fmaf(ea2, Wn1[192+k], bn1[k])));
        m = fmaf(xs1, w, m);
        k = 64 + o;
        w = fmaf(ea0, Wn1[k], fmaf(ea1, Wn1[96+k], fmaf(ea2, Wn1[192+k], bn1[k])));
        m = fmaf(xs2, w, m);
    }
    atomicAdd(&agg[d*32 + o], m);
}

// ---------------- conv1 node kernel ----------------
// h1 = relu(agg + x@root1 + b1); also re-zero agg for conv2 reuse.
__global__ __launch_bounds__(256) void node1_kernel(
    const float* __restrict__ x, const float* __restrict__ root1,
    const float* __restrict__ b1, float* __restrict__ agg,
    float* __restrict__ h1out)
{
    int gid = blockIdx.x * 256 + threadIdx.x;
    int n = gid >> 5, o = gid & 31;
    if (n >= N_NODES) return;
    float a = agg[n*32 + o];
    agg[n*32 + o] = 0.f;
    float x0 = x[n*3+0], x1 = x[n*3+1], x2 = x[n*3+2];
    float v = a + b1[o];
    v = fmaf(x0, root1[o],      v);
    v = fmaf(x1, root1[32 + o], v);
    v = fmaf(x2, root1[64 + o], v);
    h1out[n*32 + o] = fmaxf(v, 0.f);
}

// ---------------- conv2 edge kernel (dominant) ----------------
// msg[e][o] = sum_d ea[d] * (h1[src] @ Wn2_d)[o] + (h1[src] @ Bn2)[o]
// Wn2 (3x1024) + bn2 (1024) staged in 16 KB LDS.
__global__ __launch_bounds__(256) void edge2_kernel(
    const int* __restrict__ ei, const float* __restrict__ h1,
    const float* __restrict__ ea, const float* __restrict__ Wn2,
    const float* __restrict__ bn2, float* __restrict__ agg)
{
    __shared__ float sW[4096];
    for (int i = threadIdx.x; i < 3072; i += 256) sW[i] = Wn2[i];
    for (int i = threadIdx.x; i < 1024; i += 256) sW[3072 + i] = bn2[i];
    __syncthreads();

    int gid = blockIdx.x * 256 + threadIdx.x;
    int e = gid >> 5, o = gid & 31;
    if (e >= N_EDGES) return;
    int s = ei[e], d = ei[N_EDGES + e];
    float ea0 = ea[e*3+0], ea1 = ea[e*3+1], ea2 = ea[e*3+2];
    const float* __restrict__ hr = h1 + s*32;

    float a0 = 0.f, a1 = 0.f, a2 = 0.f, ab = 0.f;
    #pragma unroll 8
    for (int i = 0; i < 32; ++i) {
        float hi = hr[i];                      // wave-broadcast load
        a0 = fmaf(hi, sW[        i*32 + o], a0);
        a1 = fmaf(hi, sW[1024 +  i*32 + o], a1);
        a2 = fmaf(hi, sW[2048 +  i*32 + o], a2);
        ab = fmaf(hi, sW[3072 +  i*32 + o], ab);
    }
    float m = fmaf(ea0, a0, fmaf(ea1, a1, fmaf(ea2, a2, ab)));
    atomicAdd(&agg[d*32 + o], m);
}

// ---------------- conv2 node + FC1 + FC2 fused ----------------
__global__ __launch_bounds__(256) void node2_kernel(
    const float* __restrict__ agg2, const float* __restrict__ h1,
    const float* __restrict__ root2, const float* __restrict__ b2,
    const float* __restrict__ Wf1, const float* __restrict__ bf1,
    const float* __restrict__ Wf2, const float* __restrict__ bf2,
    float* __restrict__ out)
{
    int gid = blockIdx.x * 256 + threadIdx.x;
    int n = gid >> 5, o = gid & 31;
    if (n >= N_NODES) return;
    const float* __restrict__ hr = h1 + n*32;
    float acc = agg2[n*32 + o] + b2[o];
    #pragma unroll 8
    for (int i = 0; i < 32; ++i)
        acc = fmaf(hr[i], root2[i*32 + o], acc);
    float h2 = fmaxf(acc, 0.f);

    // FC1: needs full h2 row -> cross-lane shuffle within 32-lane group
    float acc3 = bf1[o];
    #pragma unroll
    for (int i = 0; i < 32; ++i)
        acc3 = fmaf(__shfl(h2, i, 32), Wf1[i*32 + o], acc3);
    float h3 = fmaxf(acc3, 0.f);

    // FC2: reduce h3 * Wf2 across the 32-lane group
    float p = h3 * Wf2[o];
    #pragma unroll
    for (int off = 16; off; off >>= 1) p += __shfl_down(p, off, 32);
    if (o == 0) out[n] = p + bf2[0];
}

extern "C" void kernel_launch(void* const* d_in, const int* in_sizes, int n_in,
                              void* d_out, int out_size, void* d_ws, size_t ws_size,
                              hipStream_t stream) {
    const float* x     = (const float*)d_in[0];
    const int*   ei    = (const int*)  d_in[1];   // [2, E] int32
    const float* ea    = (const float*)d_in[2];
    const float* Wn1   = (const float*)d_in[3];
    const float* bn1   = (const float*)d_in[4];
    const float* root1 = (const float*)d_in[5];
    const float* b1    = (const float*)d_in[6];
    const float* Wn2   = (const float*)d_in[7];
    const float* bn2   = (const float*)d_in[8];
    const float* root2 = (const float*)d_in[9];
    const float* b2    = (const float*)d_in[10];
    const float* Wf1   = (const float*)d_in[11];
    const float* bf1   = (const float*)d_in[12];
    const float* Wf2   = (const float*)d_in[13];
    const float* bf2   = (const float*)d_in[14];
    float* out = (float*)d_out;

    float* agg = (float*)d_ws;                 // [N, 32] accumulator (reused conv1+conv2)
    float* h1  = agg + (size_t)N_NODES * HID;  // [N, 32] hidden

    hipMemsetAsync(agg, 0, (size_t)N_NODES * HID * sizeof(float), stream);

    int edge_blocks = (N_EDGES * 32 + 255) / 256;   // 50000
    int node_blocks = (N_NODES * 32 + 255) / 256;   // 12500

    edge1_kernel<<<edge_blocks, 256, 0, stream>>>(ei, x, ea, Wn1, bn1, agg);
    node1_kernel<<<node_blocks, 256, 0, stream>>>(x, root1, b1, agg, h1);
    edge2_kernel<<<edge_blocks, 256, 0, stream>>>(ei, h1, ea, Wn2, bn2, agg);
    node2_kernel<<<node_blocks, 256, 0, stream>>>(agg, h1, root2, b2,
                                                  Wf1, bf1, Wf2, bf2, out);
}

// Round 2
// 175.274 us; speedup vs baseline: 1.5531x; 1.5531x over previous
//
#include <hip/hip_runtime.h>

#define N_NODES 100000
#define N_EDGES 400000

// ---------------- conv1 edge kernel: grid-stride, 12 weights in regs ----------------
__global__ __launch_bounds__(256) void edge1_kernel(
    const int* __restrict__ ei, const float* __restrict__ x,
    const float* __restrict__ ea, const float* __restrict__ Wn1,
    const float* __restrict__ bn1, float* __restrict__ agg)
{
    int o = threadIdx.x & 31;
    float w[3][3], bb[3];
    #pragma unroll
    for (int d = 0; d < 3; ++d) {
        #pragma unroll
        for (int d2 = 0; d2 < 3; ++d2) w[d][d2] = Wn1[d2*96 + d*32 + o];
        bb[d] = bn1[d*32 + o];
    }
    int g = (blockIdx.x * 256 + threadIdx.x) >> 5;
    int gstep = (gridDim.x * 256) >> 5;
    for (int e = g; e < N_EDGES; e += gstep) {
        int s = ei[e], d = ei[N_EDGES + e];
        float ea0 = ea[e*3+0], ea1 = ea[e*3+1], ea2 = ea[e*3+2];
        float m = 0.f;
        #pragma unroll
        for (int dd = 0; dd < 3; ++dd) {
            float wd = fmaf(ea0, w[dd][0], fmaf(ea1, w[dd][1], fmaf(ea2, w[dd][2], bb[dd])));
            m = fmaf(x[s*3 + dd], wd, m);
        }
        atomicAdd(&agg[d*32 + o], m);
    }
}

// ---------------- conv1 node kernel: node-per-thread ----------------
// h1 = relu(agg + x@root1 + b1); re-zeros agg for conv2 reuse.
__global__ __launch_bounds__(256) void node1_kernel(
    const float* __restrict__ x, const float* __restrict__ root1,
    const float* __restrict__ b1, float* __restrict__ agg,
    float* __restrict__ h1)
{
    int n = blockIdx.x * 256 + threadIdx.x;
    if (n >= N_NODES) return;
    float x0 = x[n*3+0], x1 = x[n*3+1], x2 = x[n*3+2];
    float4* ag = (float4*)(agg + (size_t)n * 32);
    float4* hv = (float4*)(h1  + (size_t)n * 32);
    const float4 z4 = make_float4(0.f, 0.f, 0.f, 0.f);
    #pragma unroll
    for (int j4 = 0; j4 < 8; ++j4) {
        float4 a = ag[j4];
        ag[j4] = z4;
        float r[4];
        #pragma unroll
        for (int k = 0; k < 4; ++k) {
            int j = j4*4 + k;                     // wave-uniform weight indices -> s_load
            float v = (&a.x)[k] + b1[j];
            v = fmaf(x0, root1[j],      v);
            v = fmaf(x1, root1[32 + j], v);
            v = fmaf(x2, root1[64 + j], v);
            r[k] = fmaxf(v, 0.f);
        }
        hv[j4] = make_float4(r[0], r[1], r[2], r[3]);
    }
}

// ---------------- conv2 edge kernel (dominant): weights in 128 VGPRs ----------------
// msg[e][o] = sum_i h1[src][i] * (ea0*W0 + ea1*W1 + ea2*W2 + B)[i][o]
__global__ __launch_bounds__(256, 3) void edge2_kernel(
    const int* __restrict__ ei, const float* __restrict__ h1,
    const float* __restrict__ ea, const float* __restrict__ Wn2,
    const float* __restrict__ bn2, float* __restrict__ agg)
{
    int o = threadIdx.x & 31;
    float w0[32], w1[32], w2[32], wb[32];
    #pragma unroll
    for (int i = 0; i < 32; ++i) {               // coalesced, once per thread
        w0[i] = Wn2[        i*32 + o];
        w1[i] = Wn2[1024 +  i*32 + o];
        w2[i] = Wn2[2048 +  i*32 + o];
        wb[i] = bn2[        i*32 + o];
    }
    int g = (blockIdx.x * 256 + threadIdx.x) >> 5;
    int gstep = (gridDim.x * 256) >> 5;
    for (int e = g; e < N_EDGES; e += gstep) {
        int s = ei[e], d = ei[N_EDGES + e];
        float ea0 = ea[e*3+0], ea1 = ea[e*3+1], ea2 = ea[e*3+2];
        const float* __restrict__ hr = h1 + (size_t)s * 32;
        float a0 = 0.f, a1 = 0.f, a2 = 0.f, ab = 0.f;
        #pragma unroll
        for (int i = 0; i < 32; ++i) {
            float hi = hr[i];                    // L1 broadcast load
            a0 = fmaf(hi, w0[i], a0);
            a1 = fmaf(hi, w1[i], a1);
            a2 = fmaf(hi, w2[i], a2);
            ab = fmaf(hi, wb[i], ab);
        }
        float m = fmaf(ea0, a0, fmaf(ea1, a1, fmaf(ea2, a2, ab)));
        atomicAdd(&agg[d*32 + o], m);
    }
}

// ---------------- conv2 node + FC1 + FC2, node-per-thread (no shfl) ----------------
__global__ __launch_bounds__(256) void node2_kernel(
    const float* __restrict__ agg2, const float* __restrict__ h1,
    const float* __restrict__ root2, const float* __restrict__ b2,
    const float* __restrict__ Wf1, const float* __restrict__ bf1,
    const float* __restrict__ Wf2, const float* __restrict__ bf2,
    float* __restrict__ out)
{
    int n = blockIdx.x * 256 + threadIdx.x;
    if (n >= N_NODES) return;
    float hr[32];
    const float4* hv = (const float4*)(h1 + (size_t)n * 32);
    #pragma unroll
    for (int j4 = 0; j4 < 8; ++j4) {
        float4 t = hv[j4];
        hr[j4*4+0] = t.x; hr[j4*4+1] = t.y; hr[j4*4+2] = t.z; hr[j4*4+3] = t.w;
    }
    const float4* av = (const float4*)(agg2 + (size_t)n * 32);
    float h2[32];
    #pragma unroll
    for (int j4 = 0; j4 < 8; ++j4) {
        float4 a = av[j4];
        #pragma unroll
        for (int k = 0; k < 4; ++k) {
            int j = j4*4 + k;
            float acc = (&a.x)[k] + b2[j];
            #pragma unroll
            for (int i = 0; i < 32; ++i)
                acc = fmaf(hr[i], root2[i*32 + j], acc);   // uniform -> s_load
            h2[j] = fmaxf(acc, 0.f);
        }
    }
    float h3[32];
    #pragma unroll
    for (int j = 0; j < 32; ++j) {
        float acc = bf1[j];
        #pragma unroll
        for (int i = 0; i < 32; ++i)
            acc = fmaf(h2[i], Wf1[i*32 + j], acc);
        h3[j] = fmaxf(acc, 0.f);
    }
    float acc = bf2[0];
    #pragma unroll
    for (int j = 0; j < 32; ++j) acc = fmaf(h3[j], Wf2[j], acc);
    out[n] = acc;
}

extern "C" void kernel_launch(void* const* d_in, const int* in_sizes, int n_in,
                              void* d_out, int out_size, void* d_ws, size_t ws_size,
                              hipStream_t stream) {
    const float* x     = (const float*)d_in[0];
    const int*   ei    = (const int*)  d_in[1];
    const float* ea    = (const float*)d_in[2];
    const float* Wn1   = (const float*)d_in[3];
    const float* bn1   = (const float*)d_in[4];
    const float* root1 = (const float*)d_in[5];
    const float* b1    = (const float*)d_in[6];
    const float* Wn2   = (const float*)d_in[7];
    const float* bn2   = (const float*)d_in[8];
    const float* root2 = (const float*)d_in[9];
    const float* b2    = (const float*)d_in[10];
    const float* Wf1   = (const float*)d_in[11];
    const float* bf1   = (const float*)d_in[12];
    const float* Wf2   = (const float*)d_in[13];
    const float* bf2   = (const float*)d_in[14];
    float* out = (float*)d_out;

    float* agg = (float*)d_ws;                       // [N,32] accumulator (reused)
    float* h1  = agg + (size_t)N_NODES * 32;         // [N,32] hidden

    hipMemsetAsync(agg, 0, (size_t)N_NODES * 32 * sizeof(float), stream);

    int node_blocks = (N_NODES + 255) / 256;         // 391

    edge1_kernel<<<2048, 256, 0, stream>>>(ei, x, ea, Wn1, bn1, agg);
    node1_kernel<<<node_blocks, 256, 0, stream>>>(x, root1, b1, agg, h1);
    edge2_kernel<<<768, 256, 0, stream>>>(ei, h1, ea, Wn2, bn2, agg);
    node2_kernel<<<node_blocks, 256, 0, stream>>>(agg, h1, root2, b2,
                                                  Wf1, bf1, Wf2, bf2, out);
}

// Round 3
// 169.345 us; speedup vs baseline: 1.6075x; 1.0350x over previous
//
#include <hip/hip_runtime.h>

#define N_NODES 100000
#define N_EDGES 400000
#define SCAN_BLOCKS ((N_NODES + 255) / 256)   // 391

// ---------- build CSR by dst: histogram ----------
__global__ __launch_bounds__(256) void hist_kernel(const int* __restrict__ ei,
                                                   int* __restrict__ deg) {
    int e = blockIdx.x * 256 + threadIdx.x;
    if (e < N_EDGES) atomicAdd(&deg[ei[N_EDGES + e]], 1);
}

// block-local exclusive scan of deg -> rowptr(local), block sums -> psum
__global__ __launch_bounds__(256) void scanA_kernel(const int* __restrict__ deg,
                                                    int* __restrict__ rowptr,
                                                    int* __restrict__ psum) {
    __shared__ int sm[256];
    int i = blockIdx.x * 256 + threadIdx.x;
    int v = (i < N_NODES) ? deg[i] : 0;
    sm[threadIdx.x] = v;
    __syncthreads();
    #pragma unroll
    for (int off = 1; off < 256; off <<= 1) {
        int t = (threadIdx.x >= off) ? sm[threadIdx.x - off] : 0;
        __syncthreads();
        sm[threadIdx.x] += t;
        __syncthreads();
    }
    if (i < N_NODES) rowptr[i] = sm[threadIdx.x] - v;   // exclusive within block
    if (threadIdx.x == 255) psum[blockIdx.x] = sm[255];
}

// scan the 391 block sums (inclusive), single block of 512
__global__ __launch_bounds__(512) void scanB_kernel(int* __restrict__ psum) {
    __shared__ int sm[512];
    int i = threadIdx.x;
    int v = (i < SCAN_BLOCKS) ? psum[i] : 0;
    sm[i] = v;
    __syncthreads();
    #pragma unroll
    for (int off = 1; off < 512; off <<= 1) {
        int t = (i >= off) ? sm[i - off] : 0;
        __syncthreads();
        sm[i] += t;
        __syncthreads();
    }
    if (i < SCAN_BLOCKS) psum[i] = sm[i];
}

// add block offsets; produce rowptr + cursor copy
__global__ __launch_bounds__(256) void scanC_kernel(const int* __restrict__ psum,
                                                    int* __restrict__ rowptr,
                                                    int* __restrict__ cursor) {
    int i = blockIdx.x * 256 + threadIdx.x;
    if (i < N_NODES) {
        int base = (blockIdx.x > 0) ? psum[blockIdx.x - 1] : 0;
        int r = rowptr[i] + base;
        rowptr[i] = r;
        cursor[i] = r;
    }
    if (i == 0) rowptr[N_NODES] = N_EDGES;
}

// scatter edge payload {ea0,ea1,ea2,src} into dst-sorted slots
__global__ __launch_bounds__(256) void scatter_kernel(const int* __restrict__ ei,
                                                      const float* __restrict__ ea,
                                                      int* __restrict__ cursor,
                                                      float4* __restrict__ edata) {
    int e = blockIdx.x * 256 + threadIdx.x;
    if (e >= N_EDGES) return;
    int s = ei[e], d = ei[N_EDGES + e];
    int pos = atomicAdd(&cursor[d], 1);
    edata[pos] = make_float4(ea[e*3], ea[e*3+1], ea[e*3+2], __int_as_float(s));
}

// ---------- conv1 aggregation + node update, fused, no atomics ----------
// thread (n,o): sum over incoming edges, 12 reg weights
__global__ __launch_bounds__(256) void conv1_kernel(const int* __restrict__ rowptr,
                                                    const float4* __restrict__ edata,
                                                    const float* __restrict__ x,
                                                    const float* __restrict__ Wn1,
                                                    const float* __restrict__ bn1,
                                                    const float* __restrict__ root1,
                                                    const float* __restrict__ b1,
                                                    float* __restrict__ h1) {
    int gid = blockIdx.x * 256 + threadIdx.x;
    int n = gid >> 5, o = gid & 31;
    if (n >= N_NODES) return;
    float W[3][3], bb[3];
    #pragma unroll
    for (int d2 = 0; d2 < 3; ++d2)
        #pragma unroll
        for (int d = 0; d < 3; ++d) W[d2][d] = Wn1[d2*96 + d*32 + o];
    #pragma unroll
    for (int d = 0; d < 3; ++d) bb[d] = bn1[d*32 + o];

    float acc = 0.f;
    int j0 = rowptr[n], j1 = rowptr[n + 1];
    for (int j = j0; j < j1; ++j) {
        float4 ed = edata[j];
        int s = __float_as_int(ed.w);
        float x0 = x[s*3], x1 = x[s*3+1], x2 = x[s*3+2];
        float wd0 = fmaf(ed.x, W[0][0], fmaf(ed.y, W[1][0], fmaf(ed.z, W[2][0], bb[0])));
        float wd1 = fmaf(ed.x, W[0][1], fmaf(ed.y, W[1][1], fmaf(ed.z, W[2][1], bb[1])));
        float wd2 = fmaf(ed.x, W[0][2], fmaf(ed.y, W[1][2], fmaf(ed.z, W[2][2], bb[2])));
        acc += fmaf(x0, wd0, fmaf(x1, wd1, x2 * wd2));
    }
    float v = acc + b1[o];
    v = fmaf(x[n*3],   root1[o],      v);
    v = fmaf(x[n*3+1], root1[32 + o], v);
    v = fmaf(x[n*3+2], root1[64 + o], v);
    h1[(size_t)n*32 + o] = fmaxf(v, 0.f);
}

// ---------- per-node precompute G2[n] = [hW0 | hW1 | hW2 | hB], float4 per (n,o) ----------
__global__ __launch_bounds__(256) void prep2_kernel(const float* __restrict__ h1,
                                                    const float* __restrict__ Wn2,
                                                    const float* __restrict__ bn2,
                                                    float4* __restrict__ G2) {
    int o = threadIdx.x & 31;
    float w0[32], w1[32], w2[32], w3[32];
    #pragma unroll
    for (int i = 0; i < 32; ++i) {
        w0[i] = Wn2[         i*32 + o];
        w1[i] = Wn2[1024 +   i*32 + o];
        w2[i] = Wn2[2048 +   i*32 + o];
        w3[i] = bn2[         i*32 + o];
    }
    int g = (blockIdx.x * 256 + threadIdx.x) >> 5;
    int gstep = (gridDim.x * 256) >> 5;
    for (int n = g; n < N_NODES; n += gstep) {
        const float* __restrict__ hr = h1 + (size_t)n * 32;
        float g0 = 0.f, g1 = 0.f, g2 = 0.f, g3 = 0.f;
        #pragma unroll
        for (int i = 0; i < 32; ++i) {
            float hi = hr[i];
            g0 = fmaf(hi, w0[i], g0);
            g1 = fmaf(hi, w1[i], g1);
            g2 = fmaf(hi, w2[i], g2);
            g3 = fmaf(hi, w3[i], g3);
        }
        G2[(size_t)n*32 + o] = make_float4(g0, g1, g2, g3);
    }
}

// ---------- conv2 aggregation + root2 + FC1 + FC2, fused, no atomics ----------
__global__ __launch_bounds__(256) void conv2_kernel(const int* __restrict__ rowptr,
                                                    const float4* __restrict__ edata,
                                                    const float4* __restrict__ G2,
                                                    const float* __restrict__ h1,
                                                    const float* __restrict__ root2,
                                                    const float* __restrict__ b2,
                                                    const float* __restrict__ Wf1,
                                                    const float* __restrict__ bf1,
                                                    const float* __restrict__ Wf2,
                                                    const float* __restrict__ bf2,
                                                    float* __restrict__ out) {
    int gid = blockIdx.x * 256 + threadIdx.x;
    int n = gid >> 5, o = gid & 31;
    if (n >= N_NODES) return;
    float acc = 0.f;
    int j0 = rowptr[n], j1 = rowptr[n + 1];
    for (int j = j0; j < j1; ++j) {
        float4 ed = edata[j];
        int s = __float_as_int(ed.w);
        float4 gg = G2[(size_t)s*32 + o];          // coalesced 512B per 32-lane group
        acc += fmaf(ed.x, gg.x, fmaf(ed.y, gg.y, fmaf(ed.z, gg.z, gg.w)));
    }
    const float* __restrict__ hr = h1 + (size_t)n * 32;
    float v = acc + b2[o];
    #pragma unroll
    for (int i = 0; i < 32; ++i) v = fmaf(hr[i], root2[i*32 + o], v);
    float h2 = fmaxf(v, 0.f);

    float a3 = bf1[o];
    #pragma unroll
    for (int i = 0; i < 32; ++i) a3 = fmaf(__shfl(h2, i, 32), Wf1[i*32 + o], a3);
    float h3 = fmaxf(a3, 0.f);

    float p = h3 * Wf2[o];
    #pragma unroll
    for (int off = 16; off; off >>= 1) p += __shfl_down(p, off, 32);
    if (o == 0) out[n] = p + bf2[0];
}

extern "C" void kernel_launch(void* const* d_in, const int* in_sizes, int n_in,
                              void* d_out, int out_size, void* d_ws, size_t ws_size,
                              hipStream_t stream) {
    const float* x     = (const float*)d_in[0];
    const int*   ei    = (const int*)  d_in[1];
    const float* ea    = (const float*)d_in[2];
    const float* Wn1   = (const float*)d_in[3];
    const float* bn1   = (const float*)d_in[4];
    const float* root1 = (const float*)d_in[5];
    const float* b1    = (const float*)d_in[6];
    const float* Wn2   = (const float*)d_in[7];
    const float* bn2   = (const float*)d_in[8];
    const float* root2 = (const float*)d_in[9];
    const float* b2    = (const float*)d_in[10];
    const float* Wf1   = (const float*)d_in[11];
    const float* bf1   = (const float*)d_in[12];
    const float* Wf2   = (const float*)d_in[13];
    const float* bf2   = (const float*)d_in[14];
    float* out = (float*)d_out;

    // workspace carve (~72 MB)
    float*  h1    = (float*)d_ws;                       // [N,32]
    float4* G2    = (float4*)(h1 + (size_t)N_NODES*32); // [N,32] float4
    float4* edata = G2 + (size_t)N_NODES*32;            // [E] float4
    int*    deg   = (int*)(edata + N_EDGES);            // [N]
    int*    rowptr= deg + N_NODES;                      // [N+1]
    int*    cursor= rowptr + N_NODES + 1;               // [N]
    int*    psum  = cursor + N_NODES;                   // [512]

    hipMemsetAsync(deg, 0, N_NODES * sizeof(int), stream);

    int eb = (N_EDGES + 255) / 256;                     // 1563
    int nb32 = (N_NODES * 32 + 255) / 256;              // 12500

    hist_kernel   <<<eb, 256, 0, stream>>>(ei, deg);
    scanA_kernel  <<<SCAN_BLOCKS, 256, 0, stream>>>(deg, rowptr, psum);
    scanB_kernel  <<<1, 512, 0, stream>>>(psum);
    scanC_kernel  <<<SCAN_BLOCKS, 256, 0, stream>>>(psum, rowptr, cursor);
    scatter_kernel<<<eb, 256, 0, stream>>>(ei, ea, cursor, edata);
    conv1_kernel  <<<nb32, 256, 0, stream>>>(rowptr, edata, x, Wn1, bn1, root1, b1, h1);
    prep2_kernel  <<<1536, 256, 0, stream>>>(h1, Wn2, bn2, G2);
    conv2_kernel  <<<nb32, 256, 0, stream>>>(rowptr, edata, G2, h1, root2, b2,
                                             Wf1, bf1, Wf2, bf2, out);
}

// Round 4
// 163.915 us; speedup vs baseline: 1.6608x; 1.0331x over previous
//
#include <hip/hip_runtime.h>

#define N_NODES 100000
#define N_EDGES 400000
#define SCAN_BLOCKS ((N_NODES + 255) / 256)   // 391

// ---------- build CSR by dst: histogram ----------
__global__ __launch_bounds__(256) void hist_kernel(const int* __restrict__ ei,
                                                   int* __restrict__ deg) {
    int e = blockIdx.x * 256 + threadIdx.x;
    if (e < N_EDGES) atomicAdd(&deg[ei[N_EDGES + e]], 1);
}

// block-local exclusive scan of deg -> rowptr(local), block sums -> psum
__global__ __launch_bounds__(256) void scanA_kernel(const int* __restrict__ deg,
                                                    int* __restrict__ rowptr,
                                                    int* __restrict__ psum) {
    __shared__ int sm[256];
    int i = blockIdx.x * 256 + threadIdx.x;
    int v = (i < N_NODES) ? deg[i] : 0;
    sm[threadIdx.x] = v;
    __syncthreads();
    #pragma unroll
    for (int off = 1; off < 256; off <<= 1) {
        int t = (threadIdx.x >= off) ? sm[threadIdx.x - off] : 0;
        __syncthreads();
        sm[threadIdx.x] += t;
        __syncthreads();
    }
    if (i < N_NODES) rowptr[i] = sm[threadIdx.x] - v;   // exclusive within block
    if (threadIdx.x == 255) psum[blockIdx.x] = sm[255];
}

// merged scanB+scanC: each block reduces psum[0..bid-1] itself, then offsets
__global__ __launch_bounds__(256) void scanBC_kernel(const int* __restrict__ psum,
                                                     int* __restrict__ rowptr,
                                                     int* __restrict__ cursor) {
    __shared__ int sm[8];
    int bid = blockIdx.x, tid = threadIdx.x;
    int acc = 0;
    for (int t = tid; t < bid; t += 256) acc += psum[t];
    // reduce 256 threads -> 1
    #pragma unroll
    for (int off = 32; off; off >>= 1) acc += __shfl_down(acc, off, 64);
    if ((tid & 63) == 0) sm[tid >> 6] = acc;
    __syncthreads();
    int base = sm[0] + sm[1] + sm[2] + sm[3];
    int i = bid * 256 + tid;
    if (i < N_NODES) {
        int r = rowptr[i] + base;
        rowptr[i] = r;
        cursor[i] = r;
    }
    if (i == 0) rowptr[N_NODES] = N_EDGES;
}

// scatter edge payload into dst-sorted slots: A={ea0,ea1,ea2,src}, B={x[s],0}
__global__ __launch_bounds__(256) void scatter_kernel(const int* __restrict__ ei,
                                                      const float* __restrict__ ea,
                                                      const float* __restrict__ x,
                                                      int* __restrict__ cursor,
                                                      float4* __restrict__ edataA,
                                                      float4* __restrict__ edataB) {
    int e = blockIdx.x * 256 + threadIdx.x;
    if (e >= N_EDGES) return;
    int s = ei[e], d = ei[N_EDGES + e];
    int pos = atomicAdd(&cursor[d], 1);
    edataA[pos] = make_float4(ea[e*3], ea[e*3+1], ea[e*3+2], __int_as_float(s));
    edataB[pos] = make_float4(x[s*3], x[s*3+1], x[s*3+2], 0.f);
}

// ---------- conv1 aggregation + node update, fused, no atomics ----------
__global__ __launch_bounds__(256) void conv1_kernel(const int* __restrict__ rowptr,
                                                    const float4* __restrict__ edataA,
                                                    const float4* __restrict__ edataB,
                                                    const float* __restrict__ x,
                                                    const float* __restrict__ Wn1,
                                                    const float* __restrict__ bn1,
                                                    const float* __restrict__ root1,
                                                    const float* __restrict__ b1,
                                                    float* __restrict__ h1) {
    int gid = blockIdx.x * 256 + threadIdx.x;
    int n = gid >> 5, o = gid & 31;
    if (n >= N_NODES) return;
    float W[3][3], bb[3];
    #pragma unroll
    for (int d2 = 0; d2 < 3; ++d2)
        #pragma unroll
        for (int d = 0; d < 3; ++d) W[d2][d] = Wn1[d2*96 + d*32 + o];
    #pragma unroll
    for (int d = 0; d < 3; ++d) bb[d] = bn1[d*32 + o];

    int j0 = rowptr[n], j1 = rowptr[n + 1];
    float acc0 = 0.f, acc1 = 0.f;
    int j = j0;
    for (; j + 2 <= j1; j += 2) {
        float4 eA0 = edataA[j],   eB0 = edataB[j];
        float4 eA1 = edataA[j+1], eB1 = edataB[j+1];
        float wd0 = fmaf(eA0.x, W[0][0], fmaf(eA0.y, W[1][0], fmaf(eA0.z, W[2][0], bb[0])));
        float wd1 = fmaf(eA0.x, W[0][1], fmaf(eA0.y, W[1][1], fmaf(eA0.z, W[2][1], bb[1])));
        float wd2 = fmaf(eA0.x, W[0][2], fmaf(eA0.y, W[1][2], fmaf(eA0.z, W[2][2], bb[2])));
        acc0 += fmaf(eB0.x, wd0, fmaf(eB0.y, wd1, eB0.z * wd2));
        float ud0 = fmaf(eA1.x, W[0][0], fmaf(eA1.y, W[1][0], fmaf(eA1.z, W[2][0], bb[0])));
        float ud1 = fmaf(eA1.x, W[0][1], fmaf(eA1.y, W[1][1], fmaf(eA1.z, W[2][1], bb[1])));
        float ud2 = fmaf(eA1.x, W[0][2], fmaf(eA1.y, W[1][2], fmaf(eA1.z, W[2][2], bb[2])));
        acc1 += fmaf(eB1.x, ud0, fmaf(eB1.y, ud1, eB1.z * ud2));
    }
    if (j < j1) {
        float4 eA0 = edataA[j], eB0 = edataB[j];
        float wd0 = fmaf(eA0.x, W[0][0], fmaf(eA0.y, W[1][0], fmaf(eA0.z, W[2][0], bb[0])));
        float wd1 = fmaf(eA0.x, W[0][1], fmaf(eA0.y, W[1][1], fmaf(eA0.z, W[2][1], bb[1])));
        float wd2 = fmaf(eA0.x, W[0][2], fmaf(eA0.y, W[1][2], fmaf(eA0.z, W[2][2], bb[2])));
        acc0 += fmaf(eB0.x, wd0, fmaf(eB0.y, wd1, eB0.z * wd2));
    }
    float v = acc0 + acc1 + b1[o];
    v = fmaf(x[n*3],   root1[o],      v);
    v = fmaf(x[n*3+1], root1[32 + o], v);
    v = fmaf(x[n*3+2], root1[64 + o], v);
    h1[(size_t)n*32 + o] = fmaxf(v, 0.f);
}

// ---------- per-node precompute G2[n] = [hW0 | hW1 | hW2 | hB] ----------
__global__ __launch_bounds__(256) void prep2_kernel(const float* __restrict__ h1,
                                                    const float* __restrict__ Wn2,
                                                    const float* __restrict__ bn2,
                                                    float4* __restrict__ G2) {
    int o = threadIdx.x & 31;
    float w0[32], w1[32], w2[32], w3[32];
    #pragma unroll
    for (int i = 0; i < 32; ++i) {
        w0[i] = Wn2[         i*32 + o];
        w1[i] = Wn2[1024 +   i*32 + o];
        w2[i] = Wn2[2048 +   i*32 + o];
        w3[i] = bn2[         i*32 + o];
    }
    int g = (blockIdx.x * 256 + threadIdx.x) >> 5;
    int gstep = (gridDim.x * 256) >> 5;
    for (int n = g; n < N_NODES; n += gstep) {
        const float* __restrict__ hr = h1 + (size_t)n * 32;
        float g0 = 0.f, g1 = 0.f, g2 = 0.f, g3 = 0.f;
        #pragma unroll
        for (int i = 0; i < 32; ++i) {
            float hi = hr[i];
            g0 = fmaf(hi, w0[i], g0);
            g1 = fmaf(hi, w1[i], g1);
            g2 = fmaf(hi, w2[i], g2);
            g3 = fmaf(hi, w3[i], g3);
        }
        G2[(size_t)n*32 + o] = make_float4(g0, g1, g2, g3);
    }
}

// ---------- conv2 aggregation (4-way MLP) + root2 + FC1 + FC2 ----------
__global__ __launch_bounds__(256) void conv2_kernel(const int* __restrict__ rowptr,
                                                    const float4* __restrict__ edataA,
                                                    const float4* __restrict__ G2,
                                                    const float* __restrict__ h1,
                                                    const float* __restrict__ root2,
                                                    const float* __restrict__ b2,
                                                    const float* __restrict__ Wf1,
                                                    const float* __restrict__ bf1,
                                                    const float* __restrict__ Wf2,
                                                    const float* __restrict__ bf2,
                                                    float* __restrict__ out) {
    int gid = blockIdx.x * 256 + threadIdx.x;
    int n = gid >> 5, o = gid & 31;
    if (n >= N_NODES) return;
    int j0 = rowptr[n], j1 = rowptr[n + 1];
    float a0 = 0.f, a1 = 0.f, a2 = 0.f, a3v = 0.f;
    int j = j0;
    for (; j + 4 <= j1; j += 4) {
        float4 e0 = edataA[j],   e1 = edataA[j+1];
        float4 e2 = edataA[j+2], e3 = edataA[j+3];
        float4 g0 = G2[(size_t)__float_as_int(e0.w)*32 + o];
        float4 g1 = G2[(size_t)__float_as_int(e1.w)*32 + o];
        float4 g2 = G2[(size_t)__float_as_int(e2.w)*32 + o];
        float4 g3 = G2[(size_t)__float_as_int(e3.w)*32 + o];
        a0 += fmaf(e0.x, g0.x, fmaf(e0.y, g0.y, fmaf(e0.z, g0.z, g0.w)));
        a1 += fmaf(e1.x, g1.x, fmaf(e1.y, g1.y, fmaf(e1.z, g1.z, g1.w)));
        a2 += fmaf(e2.x, g2.x, fmaf(e2.y, g2.y, fmaf(e2.z, g2.z, g2.w)));
        a3v += fmaf(e3.x, g3.x, fmaf(e3.y, g3.y, fmaf(e3.z, g3.z, g3.w)));
    }
    for (; j < j1; ++j) {
        float4 e0 = edataA[j];
        float4 g0 = G2[(size_t)__float_as_int(e0.w)*32 + o];
        a0 += fmaf(e0.x, g0.x, fmaf(e0.y, g0.y, fmaf(e0.z, g0.z, g0.w)));
    }
    float acc = (a0 + a1) + (a2 + a3v);

    const float* __restrict__ hr = h1 + (size_t)n * 32;
    float v = acc + b2[o];
    #pragma unroll
    for (int i = 0; i < 32; ++i) v = fmaf(hr[i], root2[i*32 + o], v);
    float h2 = fmaxf(v, 0.f);

    float a3 = bf1[o];
    #pragma unroll
    for (int i = 0; i < 32; ++i) a3 = fmaf(__shfl(h2, i, 32), Wf1[i*32 + o], a3);
    float h3 = fmaxf(a3, 0.f);

    float p = h3 * Wf2[o];
    #pragma unroll
    for (int off = 16; off; off >>= 1) p += __shfl_down(p, off, 32);
    if (o == 0) out[n] = p + bf2[0];
}

extern "C" void kernel_launch(void* const* d_in, const int* in_sizes, int n_in,
                              void* d_out, int out_size, void* d_ws, size_t ws_size,
                              hipStream_t stream) {
    const float* x     = (const float*)d_in[0];
    const int*   ei    = (const int*)  d_in[1];
    const float* ea    = (const float*)d_in[2];
    const float* Wn1   = (const float*)d_in[3];
    const float* bn1   = (const float*)d_in[4];
    const float* root1 = (const float*)d_in[5];
    const float* b1    = (const float*)d_in[6];
    const float* Wn2   = (const float*)d_in[7];
    const float* bn2   = (const float*)d_in[8];
    const float* root2 = (const float*)d_in[9];
    const float* b2    = (const float*)d_in[10];
    const float* Wf1   = (const float*)d_in[11];
    const float* bf1   = (const float*)d_in[12];
    const float* Wf2   = (const float*)d_in[13];
    const float* bf2   = (const float*)d_in[14];
    float* out = (float*)d_out;

    // workspace carve (~78 MB)
    float*  h1     = (float*)d_ws;                        // [N,32]
    float4* G2     = (float4*)(h1 + (size_t)N_NODES*32);  // [N,32] float4
    float4* edataA = G2 + (size_t)N_NODES*32;             // [E]
    float4* edataB = edataA + N_EDGES;                    // [E]
    int*    deg    = (int*)(edataB + N_EDGES);            // [N]
    int*    rowptr = deg + N_NODES;                       // [N+1]
    int*    cursor = rowptr + N_NODES + 1;                // [N]
    int*    psum   = cursor + N_NODES;                    // [SCAN_BLOCKS]

    hipMemsetAsync(deg, 0, N_NODES * sizeof(int), stream);

    int eb = (N_EDGES + 255) / 256;                       // 1563
    int nb32 = (N_NODES * 32 + 255) / 256;                // 12500

    hist_kernel   <<<eb, 256, 0, stream>>>(ei, deg);
    scanA_kernel  <<<SCAN_BLOCKS, 256, 0, stream>>>(deg, rowptr, psum);
    scanBC_kernel <<<SCAN_BLOCKS, 256, 0, stream>>>(psum, rowptr, cursor);
    scatter_kernel<<<eb, 256, 0, stream>>>(ei, ea, x, cursor, edataA, edataB);
    conv1_kernel  <<<nb32, 256, 0, stream>>>(rowptr, edataA, edataB, x, Wn1, bn1, root1, b1, h1);
    prep2_kernel  <<<1536, 256, 0, stream>>>(h1, Wn2, bn2, G2);
    conv2_kernel  <<<nb32, 256, 0, stream>>>(rowptr, edataA, G2, h1, root2, b2,
                                             Wf1, bf1, Wf2, bf2, out);
}